// Round 2
// baseline (304.885 us; speedup 1.0000x reference)
//
#include <hip/hip_runtime.h>
#include <math.h>

#define IMG 256
#define N_ANG 360
#define N_DET 256
#define N_SAMP 256
// VOX = 2.0

struct W9 { float w[9]; };

__device__ __forceinline__ int refl(int i, int L) {
    if (i < 0) i = -i;
    if (i >= L) i = 2 * (L - 1) - i;
    return i;
}

// Direct 2D Gaussian blur with reflect indexing (== separable blur w/ reflect pad).
__global__ void blur2d_k(const float* __restrict__ in, float* __restrict__ out,
                         W9 wt, int r, float scale) {
    int x = threadIdx.x;
    int y = blockIdx.x;
    int b = blockIdx.y;
    const float* src = in + b * IMG * IMG;
    float acc = 0.f;
    for (int dy = -r; dy <= r; ++dy) {
        int yy = refl(y + dy, IMG);
        float wy = wt.w[dy + r];
        float rowacc = 0.f;
        const float* rowp = src + yy * IMG;
        for (int dx = -r; dx <= r; ++dx) {
            int xx = refl(x + dx, IMG);
            rowacc += wt.w[dx + r] * rowp[xx];
        }
        acc += wy * rowacc;
    }
    out[b * IMG * IMG + y * IMG + x] = acc * scale;
}

// Parallel-beam projection of BOTH blurred maps (shared geometry).
// Block = 1024 threads: 256 detectors x 4 sample-chunks of 64. LDS reduce.
// Valid-mask compares replicated in f64 (discontinuous); bilinear weights in
// f32 (continuous in ix/iy, so rounding there is harmless).
__global__ __launch_bounds__(1024) void proj_k(
        const float* __restrict__ imgb, const float* __restrict__ attb,
        float* __restrict__ sino_i, float* __restrict__ sino_a) {
    int t = threadIdx.x;
    int d = t & 255;
    int chunk = t >> 8;           // 0..3
    int a = blockIdx.x;
    int b = blockIdx.y;

    double theta = M_PI * (double)a / (double)N_ANG;
    double c = cos(theta), sn = sin(theta);
    double rr = ((double)d - 127.5) * 2.0;
    double rc = rr * c;           // loop-invariant (same rounding as per-iter)
    double rs = rr * sn;

    const float* __restrict__ ip = imgb + b * IMG * IMG;
    const float* __restrict__ ap = attb + b * IMG * IMG;

    float acc_i = 0.f, acc_a = 0.f;
    int k0 = chunk * 64;
    #pragma unroll 4
    for (int k = k0; k < k0 + 64; ++k) {
        double ss = (double)(2 * k - 255);          // exact: (k-127.5)*2
        double x = rc - ss * sn;                     // (r*c) - (s*sn), numpy order
        double y = rs + ss * c;
        double ixd = x * 0.5 + 127.5;                // single rounding, == x/VOX + 127.5
        double iyd = y * 0.5 + 127.5;
        if (ixd >= 0.0 && ixd <= 255.0 && iyd >= 0.0 && iyd <= 255.0) {
            int j0 = (int)ixd; j0 = min(j0, IMG - 2);
            int i0 = (int)iyd; i0 = min(i0, IMG - 2);
            float fx = (float)ixd - (float)j0;
            float fy = (float)iyd - (float)i0;
            float gx = 1.f - fx, gy = 1.f - fy;
            float w00 = gy * gx, w01 = gy * fx, w10 = fy * gx, w11 = fy * fx;
            int o = i0 * IMG + j0;
            acc_i += w00 * ip[o] + w01 * ip[o + 1] + w10 * ip[o + IMG] + w11 * ip[o + IMG + 1];
            acc_a += w00 * ap[o] + w01 * ap[o + 1] + w10 * ap[o + IMG] + w11 * ap[o + IMG + 1];
        }
    }

    __shared__ float red_i[1024];
    __shared__ float red_a[1024];
    red_i[t] = acc_i;
    red_a[t] = acc_a;
    __syncthreads();
    if (t < 256) {
        float si = (red_i[t] + red_i[t + 256]) + (red_i[t + 512] + red_i[t + 768]);
        float sa = (red_a[t] + red_a[t + 256]) + (red_a[t + 512] + red_a[t + 768]);
        int idx = (b * N_ANG + a) * N_DET + t;
        sino_i[idx] = si * 2.0f;   // * VOX
        sino_a[idx] = sa * 2.0f;
    }
}

// Attenuate + final blur along DETECTOR axis + transpose to out[b][det][ang].
__global__ void finish_k(const float* __restrict__ sino_i, const float* __restrict__ sino_a,
                         float* __restrict__ out, W9 wt) {
    int tid = blockIdx.x * blockDim.x + threadIdx.x;
    if (tid >= 2 * N_DET * N_ANG) return;
    int a = tid % N_ANG;
    int t = tid / N_ANG;
    int d = t % N_DET;
    int b = t / N_DET;
    float acc = 0.f;
    for (int i = -2; i <= 2; ++i) {
        int dd = refl(d + i, N_DET);
        int idx = (b * N_ANG + a) * N_DET + dd;
        float v = sino_i[idx] * expf(-sino_a[idx] * 2.0f);
        acc += wt.w[i + 2] * v;
    }
    out[tid] = acc;  // tid == (b*N_DET + d)*N_ANG + a
}

static void gauss_w(W9* wt, double sigma, int r) {
    double tmp[9];
    double s = 0.0;
    for (int i = -r; i <= r; ++i) {
        double v = exp(-0.5 * ((double)i / sigma) * ((double)i / sigma));
        tmp[i + r] = v;
        s += v;
    }
    for (int i = 0; i < 2 * r + 1; ++i) wt->w[i] = (float)(tmp[i] / s);
    for (int i = 2 * r + 1; i < 9; ++i) wt->w[i] = 0.f;
}

extern "C" void kernel_launch(void* const* d_in, const int* in_sizes, int n_in,
                              void* d_out, int out_size, void* d_ws, size_t ws_size,
                              hipStream_t stream) {
    const float* img = (const float*)d_in[0];
    const float* att = (const float*)d_in[1];
    float* out = (float*)d_out;

    char* ws = (char*)d_ws;
    float* imgb   = (float*)(ws);                       // 512 KiB
    float* attb   = (float*)(ws + 524288);              // 512 KiB
    float* sino_i = (float*)(ws + 1048576);             // 720 KiB
    float* sino_a = (float*)(ws + 1785856);             // 720 KiB

    double sqrt_log2 = sqrt(log(2.0));
    double sigma_img = 4.0 / (4.0 * sqrt_log2) / 2.0;   // ~0.60056, r=2
    double sigma_att = 4.0 / (2.0 * sqrt_log2) / 2.0;   // ~1.20112, r=4
    W9 wimg, watt;
    gauss_w(&wimg, sigma_img, 2);
    gauss_w(&watt, sigma_att, 4);

    blur2d_k<<<dim3(IMG, 2), IMG, 0, stream>>>(img, imgb, wimg, 2, 1.0f);
    blur2d_k<<<dim3(IMG, 2), IMG, 0, stream>>>(att, attb, watt, 4, 0.01f);
    proj_k<<<dim3(N_ANG, 2), 1024, 0, stream>>>(imgb, attb, sino_i, sino_a);

    int total = 2 * N_DET * N_ANG;
    finish_k<<<(total + 255) / 256, 256, 0, stream>>>(sino_i, sino_a, out, wimg);
}

// Round 3
// 150.797 us; speedup vs baseline: 2.0218x; 2.0218x over previous
//
#include <hip/hip_runtime.h>
#include <math.h>

#define IMG 256
#define N_ANG 360
#define N_DET 256
#define N_SAMP 256
// VOX = 2.0

struct W9 { float w[9]; };

__device__ __forceinline__ int refl(int i, int L) {
    if (i < 0) i = -i;
    if (i >= L) i = 2 * (L - 1) - i;
    return i;
}

// Direct 2D Gaussian blur with reflect indexing, writing one component of a
// float4-interleaved packed image. out4 points at the component.
__global__ void blur2d_pack_k(const float* __restrict__ in, float* __restrict__ out4,
                              W9 wt, int r, float scale) {
    int x = threadIdx.x;
    int y = blockIdx.x;
    float acc = 0.f;
    for (int dy = -r; dy <= r; ++dy) {
        int yy = refl(y + dy, IMG);
        const float* rowp = in + yy * IMG;
        float ra = 0.f;
        for (int dx = -r; dx <= r; ++dx) ra += wt.w[dx + r] * rowp[refl(x + dx, IMG)];
        acc += wt.w[dy + r] * ra;
    }
    out4[(y * IMG + x) * 4] = acc * scale;
}

template <typename P>
__device__ __forceinline__ int lastTrue(P p) {     // pred true-set is a prefix of [0,255]
    if (!p(0)) return -1;
    if (p(255)) return 255;
    int lo = 0, hi = 255;
    while (lo < hi) { int m = (lo + hi + 1) >> 1; if (p(m)) lo = m; else hi = m - 1; }
    return lo;
}
template <typename P>
__device__ __forceinline__ int firstTrue(P p) {    // pred true-set is a suffix of [0,255]
    if (!p(255)) return 256;
    if (p(0)) return 0;
    int lo = 0, hi = 255;
    while (lo < hi) { int m = (lo + hi) >> 1; if (p(m)) hi = m; else lo = m + 1; }
    return lo;
}

// Projection: grid (a=360, kt=2), block 512 = 256 detectors x 2 k-chunks of 64.
// Exact f64 numpy-order mask reduced to an interval ONCE per ray (monotone in k);
// inner loop is pure f32 with float4 taps covering 2 batches x 2 maps.
__global__ __launch_bounds__(512) void proj_k(const float4* __restrict__ pk,
                                              float4* __restrict__ part4) {
    int t = threadIdx.x;
    int d = t & 255;
    int kc = t >> 8;                  // 0/1
    int a = blockIdx.x;
    int kt = blockIdx.y;              // 0/1
    int k0 = kt * 128 + kc * 64;

    double theta = M_PI * (double)a / 360.0;
    double c = cos(theta), sn = sin(theta);
    double rr = (double)(2 * d - 255);
    double rc = __dmul_rn(rr, c), rs = __dmul_rn(rr, sn);

    auto evIx = [&](int k) -> double {
        double ss = (double)(2 * k - 255);
        return __dadd_rn(__dmul_rn(__dsub_rn(rc, __dmul_rn(ss, sn)), 0.5), 127.5);
    };
    auto evIy = [&](int k) -> double {
        double ss = (double)(2 * k - 255);
        return __dadd_rn(__dmul_rn(__dadd_rn(rs, __dmul_rn(ss, c)), 0.5), 127.5);
    };

    // ix is non-increasing in k (slope -sn <= 0); iy slope = +c.
    int khiA = lastTrue([&](int k) { return evIx(k) >= 0.0; });
    int kloA = firstTrue([&](int k) { return evIx(k) <= 255.0; });
    int kloB, khiB;
    if (c > 0.0) {
        kloB = firstTrue([&](int k) { return evIy(k) >= 0.0; });
        khiB = lastTrue([&](int k) { return evIy(k) <= 255.0; });
    } else {
        khiB = lastTrue([&](int k) { return evIy(k) >= 0.0; });
        kloB = firstTrue([&](int k) { return evIy(k) <= 255.0; });
    }
    int klo = max(kloA, kloB);
    int khi = min(khiA, khiB);

    // f32 linear model of the exact geometry, centered at k=128.
    float x0f = (float)evIx(128);
    float y0f = (float)evIy(128);
    float dxf = -(float)sn;
    float dyf = (float)c;

    int jlo = max(klo - k0, 0), jhi = min(khi - k0, 63);
    int jl = jlo, jh = jhi;
    #pragma unroll
    for (int off = 32; off; off >>= 1) {           // wave-uniform bounds
        jl = min(jl, __shfl_xor(jl, off));
        jh = max(jh, __shfl_xor(jh, off));
    }

    float4 acc = make_float4(0.f, 0.f, 0.f, 0.f);
    if (jl <= jh) {
        float kf = (float)(k0 + jl - 128);
        for (int j = jl; j <= jh; ++j) {
            float ix = fmaf(kf, dxf, x0f);
            float iy = fmaf(kf, dyf, y0f);
            kf += 1.0f;
            int j0 = (int)ix; j0 = min(max(j0, 0), 254);
            int i0 = (int)iy; i0 = min(max(i0, 0), 254);
            float fx = ix - (float)j0;
            float fy = iy - (float)i0;
            float m = (j >= jlo && j <= jhi) ? 2.0f : 0.0f;   // valid * VOX
            float gx = (1.f - fx) * m, fxm = fx * m;
            float gy = 1.f - fy;
            float w00 = gy * gx, w01 = gy * fxm, w10 = fy * gx, w11 = fy * fxm;
            const float4* p = pk + (i0 << 8) + j0;
            float4 t00 = p[0], t01 = p[1], t10 = p[IMG], t11 = p[IMG + 1];
            acc.x += w00 * t00.x + w01 * t01.x + w10 * t10.x + w11 * t11.x;
            acc.y += w00 * t00.y + w01 * t01.y + w10 * t10.y + w11 * t11.y;
            acc.z += w00 * t00.z + w01 * t01.z + w10 * t10.z + w11 * t11.z;
            acc.w += w00 * t00.w + w01 * t01.w + w10 * t10.w + w11 * t11.w;
        }
    }

    __shared__ float4 red[512];
    red[t] = acc;
    __syncthreads();
    if (t < 256) {
        float4 u = red[t], v = red[t + 256];
        u.x += v.x; u.y += v.y; u.z += v.z; u.w += v.w;
        part4[(kt * N_ANG + a) * N_DET + t] = u;
    }
}

// kt-sum + attenuation + detector-axis blur + transpose.
// grid = b*360+a (720 blocks), block = 256 detectors.
__global__ __launch_bounds__(256) void finish_k(const float4* __restrict__ part4,
                                                float* __restrict__ out, W9 wt) {
    int d = threadIdx.x;
    int ba = blockIdx.x;
    int b = ba / N_ANG, a = ba % N_ANG;
    float4 s = make_float4(0.f, 0.f, 0.f, 0.f);
    #pragma unroll
    for (int kt = 0; kt < 2; ++kt) {
        float4 q = part4[(kt * N_ANG + a) * N_DET + d];
        s.x += q.x; s.y += q.y; s.z += q.z; s.w += q.w;
    }
    float si = b ? s.z : s.x;
    float sa = b ? s.w : s.y;
    __shared__ float vb[N_DET];
    vb[d] = si * expf(-sa * 2.0f);     // * exp(-att_sino * VOX)
    __syncthreads();
    float acc = 0.f;
    #pragma unroll
    for (int i = -2; i <= 2; ++i) acc += wt.w[i + 2] * vb[refl(d + i, N_DET)];
    out[(b * N_DET + d) * N_ANG + a] = acc;
}

static void gauss_w(W9* wt, double sigma, int r) {
    double tmp[9];
    double s = 0.0;
    for (int i = -r; i <= r; ++i) {
        double v = exp(-0.5 * ((double)i / sigma) * ((double)i / sigma));
        tmp[i + r] = v;
        s += v;
    }
    for (int i = 0; i < 2 * r + 1; ++i) wt->w[i] = (float)(tmp[i] / s);
    for (int i = 2 * r + 1; i < 9; ++i) wt->w[i] = 0.f;
}

extern "C" void kernel_launch(void* const* d_in, const int* in_sizes, int n_in,
                              void* d_out, int out_size, void* d_ws, size_t ws_size,
                              hipStream_t stream) {
    const float* img = (const float*)d_in[0];
    const float* att = (const float*)d_in[1];
    float* out = (float*)d_out;

    char* ws = (char*)d_ws;
    float* pk = (float*)ws;                                  // 256*256 float4 = 1 MiB
    float4* part4 = (float4*)(ws + (1 << 20));               // 2*360*256*16 = 2.95 MiB

    double sqrt_log2 = sqrt(log(2.0));
    double sigma_img = 4.0 / (4.0 * sqrt_log2) / 2.0;        // ~0.60056, r=2
    double sigma_att = 4.0 / (2.0 * sqrt_log2) / 2.0;        // ~1.20112, r=4
    W9 wimg, watt;
    gauss_w(&wimg, sigma_img, 2);
    gauss_w(&watt, sigma_att, 4);

    // packed components: {img_b0, att_b0*0.01, img_b1, att_b1*0.01}
    blur2d_pack_k<<<IMG, IMG, 0, stream>>>(img,          pk + 0, wimg, 2, 1.0f);
    blur2d_pack_k<<<IMG, IMG, 0, stream>>>(att,          pk + 1, watt, 4, 0.01f);
    blur2d_pack_k<<<IMG, IMG, 0, stream>>>(img + 65536,  pk + 2, wimg, 2, 1.0f);
    blur2d_pack_k<<<IMG, IMG, 0, stream>>>(att + 65536,  pk + 3, watt, 4, 0.01f);

    proj_k<<<dim3(N_ANG, 2), 512, 0, stream>>>((const float4*)pk, part4);

    finish_k<<<2 * N_ANG, N_DET, 0, stream>>>(part4, out, wimg);
}

// Round 4
// 122.152 us; speedup vs baseline: 2.4960x; 1.2345x over previous
//
#include <hip/hip_runtime.h>
#include <math.h>

#define IMG 256
#define N_ANG 360
#define N_DET 256
#define N_SAMP 256
// VOX = 2.0

struct W9 { float w[9]; };

__device__ __forceinline__ int refl(int i, int L) {
    if (i < 0) i = -i;
    if (i >= L) i = 2 * (L - 1) - i;
    return i;
}

// Direct 2D Gaussian blur with reflect indexing, writing one component of a
// float4-interleaved packed image. out4 points at the component.
__global__ void blur2d_pack_k(const float* __restrict__ in, float* __restrict__ out4,
                              W9 wt, int r, float scale) {
    int x = threadIdx.x;
    int y = blockIdx.x;
    float acc = 0.f;
    for (int dy = -r; dy <= r; ++dy) {
        int yy = refl(y + dy, IMG);
        const float* rowp = in + yy * IMG;
        float ra = 0.f;
        for (int dx = -r; dx <= r; ++dx) ra += wt.w[dx + r] * rowp[refl(x + dx, IMG)];
        acc += wt.w[dy + r] * ra;
    }
    out4[(y * IMG + x) * 4] = acc * scale;
}

template <typename P>
__device__ __forceinline__ int lastTrue(P p) {     // pred true-set is a prefix of [0,255]
    if (!p(0)) return -1;
    if (p(255)) return 255;
    int lo = 0, hi = 255;
    while (lo < hi) { int m = (lo + hi + 1) >> 1; if (p(m)) lo = m; else hi = m - 1; }
    return lo;
}
template <typename P>
__device__ __forceinline__ int firstTrue(P p) {    // pred true-set is a suffix of [0,255]
    if (!p(255)) return 256;
    if (p(0)) return 0;
    int lo = 0, hi = 255;
    while (lo < hi) { int m = (lo + hi) >> 1; if (p(m)) hi = m; else lo = m + 1; }
    return lo;
}

// ---------------- H-mode: |sin| <= |cos|  (a in [0,90] U [270,359]) --------
// lanes = detectors (row step per lane = |sn| <= 0.707).
// grid (181, kt=2), block 512 = 256 det x 2 k-chunks. LDS reduce.
__global__ __launch_bounds__(512) void proj_h_k(const float4* __restrict__ pk,
                                                float4* __restrict__ part4) {
    int t = threadIdx.x;
    int d = t & 255;
    int kc = t >> 8;                  // 0/1
    int bx = blockIdx.x;
    int a = (bx <= 90) ? bx : bx + 179;
    int kt = blockIdx.y;              // 0/1
    int k0 = kt * 128 + kc * 64;

    double theta = M_PI * (double)a / 360.0;
    double c = cos(theta), sn = sin(theta);
    double rr = (double)(2 * d - 255);
    double rc = __dmul_rn(rr, c), rs = __dmul_rn(rr, sn);

    auto evIx = [&](int k) -> double {
        double ss = (double)(2 * k - 255);
        return __dadd_rn(__dmul_rn(__dsub_rn(rc, __dmul_rn(ss, sn)), 0.5), 127.5);
    };
    auto evIy = [&](int k) -> double {
        double ss = (double)(2 * k - 255);
        return __dadd_rn(__dmul_rn(__dadd_rn(rs, __dmul_rn(ss, c)), 0.5), 127.5);
    };

    // ix is non-increasing in k (slope -sn <= 0); iy slope = +c.
    int khiA = lastTrue([&](int k) { return evIx(k) >= 0.0; });
    int kloA = firstTrue([&](int k) { return evIx(k) <= 255.0; });
    int kloB, khiB;
    if (c > 0.0) {
        kloB = firstTrue([&](int k) { return evIy(k) >= 0.0; });
        khiB = lastTrue([&](int k) { return evIy(k) <= 255.0; });
    } else {
        khiB = lastTrue([&](int k) { return evIy(k) >= 0.0; });
        kloB = firstTrue([&](int k) { return evIy(k) <= 255.0; });
    }
    int klo = max(kloA, kloB);
    int khi = min(khiA, khiB);

    // f32 linear model of the exact geometry, centered at k=128.
    float x0f = (float)evIx(128);
    float y0f = (float)evIy(128);
    float dxf = -(float)sn;
    float dyf = (float)c;

    int jlo = max(klo - k0, 0), jhi = min(khi - k0, 63);
    int jl = jlo, jh = jhi;
    #pragma unroll
    for (int off = 32; off; off >>= 1) {           // wave-uniform bounds
        jl = min(jl, __shfl_xor(jl, off));
        jh = max(jh, __shfl_xor(jh, off));
    }

    float4 acc = make_float4(0.f, 0.f, 0.f, 0.f);
    if (jl <= jh) {
        float kf = (float)(k0 + jl - 128);
        for (int j = jl; j <= jh; ++j) {
            float ix = fmaf(kf, dxf, x0f);
            float iy = fmaf(kf, dyf, y0f);
            kf += 1.0f;
            int j0 = (int)ix; j0 = min(max(j0, 0), 254);
            int i0 = (int)iy; i0 = min(max(i0, 0), 254);
            float fx = ix - (float)j0;
            float fy = iy - (float)i0;
            float m = (j >= jlo && j <= jhi) ? 2.0f : 0.0f;   // valid * VOX
            float gx = (1.f - fx) * m, fxm = fx * m;
            float gy = 1.f - fy;
            float w00 = gy * gx, w01 = gy * fxm, w10 = fy * gx, w11 = fy * fxm;
            const float4* p = pk + (i0 << 8) + j0;
            float4 t00 = p[0], t01 = p[1], t10 = p[IMG], t11 = p[IMG + 1];
            acc.x += w00 * t00.x + w01 * t01.x + w10 * t10.x + w11 * t11.x;
            acc.y += w00 * t00.y + w01 * t01.y + w10 * t10.y + w11 * t11.y;
            acc.z += w00 * t00.z + w01 * t01.z + w10 * t10.z + w11 * t11.z;
            acc.w += w00 * t00.w + w01 * t01.w + w10 * t10.w + w11 * t11.w;
        }
    }

    __shared__ float4 red[512];
    red[t] = acc;
    __syncthreads();
    if (t < 256) {
        float4 u = red[t], v = red[t + 256];
        u.x += v.x; u.y += v.y; u.z += v.z; u.w += v.w;
        part4[(kt * N_ANG + a) * N_DET + t] = u;
    }
}

// ---------------- V-mode: |sin| > |cos|  (a in [91,269]) -------------------
// lanes = samples k along one ray (row step per lane = |c| < 0.707).
// grid (179, 32), block 512 = 8 waves = 8 rays; lane = k (4 samples/lane).
// Validity evaluated per-sample in exact numpy-order f64.
__global__ __launch_bounds__(512) void proj_v_k(const float4* __restrict__ pk,
                                                float4* __restrict__ part4) {
    int t = threadIdx.x;
    int lane = t & 63;
    int w = t >> 6;
    int a = 91 + blockIdx.x;
    int d = blockIdx.y * 8 + w;

    double theta = M_PI * (double)a / 360.0;
    double c = cos(theta), sn = sin(theta);
    double rr = (double)(2 * d - 255);
    double rc = __dmul_rn(rr, c), rs = __dmul_rn(rr, sn);

    float4 acc = make_float4(0.f, 0.f, 0.f, 0.f);
    #pragma unroll
    for (int j = 0; j < 4; ++j) {
        int k = j * 64 + lane;
        double ss = (double)(2 * k - 255);
        double x = __dsub_rn(rc, __dmul_rn(ss, sn));
        double y = __dadd_rn(rs, __dmul_rn(ss, c));
        double ixd = __dadd_rn(__dmul_rn(x, 0.5), 127.5);
        double iyd = __dadd_rn(__dmul_rn(y, 0.5), 127.5);
        bool valid = (ixd >= 0.0) && (ixd <= 255.0) && (iyd >= 0.0) && (iyd <= 255.0);
        int j0 = (int)ixd; j0 = min(max(j0, 0), 254);
        int i0 = (int)iyd; i0 = min(max(i0, 0), 254);
        float fx = (float)ixd - (float)j0;
        float fy = (float)iyd - (float)i0;
        float m = valid ? 2.0f : 0.0f;                 // valid * VOX
        float gx = (1.f - fx) * m, fxm = fx * m;
        float gy = 1.f - fy;
        float w00 = gy * gx, w01 = gy * fxm, w10 = fy * gx, w11 = fy * fxm;
        const float4* p = pk + (i0 << 8) + j0;
        float4 t00 = p[0], t01 = p[1], t10 = p[IMG], t11 = p[IMG + 1];
        acc.x += w00 * t00.x + w01 * t01.x + w10 * t10.x + w11 * t11.x;
        acc.y += w00 * t00.y + w01 * t01.y + w10 * t10.y + w11 * t11.y;
        acc.z += w00 * t00.z + w01 * t01.z + w10 * t10.z + w11 * t11.z;
        acc.w += w00 * t00.w + w01 * t01.w + w10 * t10.w + w11 * t11.w;
    }

    #pragma unroll
    for (int off = 32; off; off >>= 1) {
        acc.x += __shfl_xor(acc.x, off);
        acc.y += __shfl_xor(acc.y, off);
        acc.z += __shfl_xor(acc.z, off);
        acc.w += __shfl_xor(acc.w, off);
    }
    if (lane == 0) {
        int idx = a * N_DET + d;
        part4[idx] = acc;                                          // kt=0 slot
        part4[N_ANG * N_DET + idx] = make_float4(0.f, 0.f, 0.f, 0.f); // kt=1
    }
}

// kt-sum + attenuation + detector-axis blur + transpose.
__global__ __launch_bounds__(256) void finish_k(const float4* __restrict__ part4,
                                                float* __restrict__ out, W9 wt) {
    int d = threadIdx.x;
    int ba = blockIdx.x;
    int b = ba / N_ANG, a = ba % N_ANG;
    float4 s = make_float4(0.f, 0.f, 0.f, 0.f);
    #pragma unroll
    for (int kt = 0; kt < 2; ++kt) {
        float4 q = part4[(kt * N_ANG + a) * N_DET + d];
        s.x += q.x; s.y += q.y; s.z += q.z; s.w += q.w;
    }
    float si = b ? s.z : s.x;
    float sa = b ? s.w : s.y;
    __shared__ float vb[N_DET];
    vb[d] = si * expf(-sa * 2.0f);     // * exp(-att_sino * VOX)
    __syncthreads();
    float acc = 0.f;
    #pragma unroll
    for (int i = -2; i <= 2; ++i) acc += wt.w[i + 2] * vb[refl(d + i, N_DET)];
    out[(b * N_DET + d) * N_ANG + a] = acc;
}

static void gauss_w(W9* wt, double sigma, int r) {
    double tmp[9];
    double s = 0.0;
    for (int i = -r; i <= r; ++i) {
        double v = exp(-0.5 * ((double)i / sigma) * ((double)i / sigma));
        tmp[i + r] = v;
        s += v;
    }
    for (int i = 0; i < 2 * r + 1; ++i) wt->w[i] = (float)(tmp[i] / s);
    for (int i = 2 * r + 1; i < 9; ++i) wt->w[i] = 0.f;
}

extern "C" void kernel_launch(void* const* d_in, const int* in_sizes, int n_in,
                              void* d_out, int out_size, void* d_ws, size_t ws_size,
                              hipStream_t stream) {
    const float* img = (const float*)d_in[0];
    const float* att = (const float*)d_in[1];
    float* out = (float*)d_out;

    char* ws = (char*)d_ws;
    float* pk = (float*)ws;                                  // 256*256 float4 = 1 MiB
    float4* part4 = (float4*)(ws + (1 << 20));               // 2*360*256*16 = 2.95 MiB

    double sqrt_log2 = sqrt(log(2.0));
    double sigma_img = 4.0 / (4.0 * sqrt_log2) / 2.0;        // ~0.60056, r=2
    double sigma_att = 4.0 / (2.0 * sqrt_log2) / 2.0;        // ~1.20112, r=4
    W9 wimg, watt;
    gauss_w(&wimg, sigma_img, 2);
    gauss_w(&watt, sigma_att, 4);

    // packed components: {img_b0, att_b0*0.01, img_b1, att_b1*0.01}
    blur2d_pack_k<<<IMG, IMG, 0, stream>>>(img,          pk + 0, wimg, 2, 1.0f);
    blur2d_pack_k<<<IMG, IMG, 0, stream>>>(att,          pk + 1, watt, 4, 0.01f);
    blur2d_pack_k<<<IMG, IMG, 0, stream>>>(img + 65536,  pk + 2, wimg, 2, 1.0f);
    blur2d_pack_k<<<IMG, IMG, 0, stream>>>(att + 65536,  pk + 3, watt, 4, 0.01f);

    proj_h_k<<<dim3(181, 2), 512, 0, stream>>>((const float4*)pk, part4);
    proj_v_k<<<dim3(179, 32), 512, 0, stream>>>((const float4*)pk, part4);

    finish_k<<<2 * N_ANG, N_DET, 0, stream>>>(part4, out, wimg);
}

// Round 5
// 84.600 us; speedup vs baseline: 3.6038x; 1.4439x over previous
//
#include <hip/hip_runtime.h>
#include <math.h>

#define IMG 256
#define N_ANG 360
#define N_DET 256
// VOX = 2.0

#define NH_BLOCKS 362              // 181 H-angles x 2 k-tiles
#define NV_BLOCKS (179 * 32)       // 179 V-angles x 32 detector-groups
#define EPS 1e-3f                  // f32-vs-f64 geometry margin (bound ~6e-5)

struct W9 { float w[9]; };
struct AngTab { double c, sn; float cf, snf; float pad0, pad1; };   // 32 B

__device__ __forceinline__ int refl(int i, int L) {
    if (i < 0) i = -i;
    if (i >= L) i = 2 * (L - 1) - i;
    return i;
}

// Per-angle sin/cos table (f64 for exact fallback, f32 for the fast path).
__global__ void tables_k(AngTab* __restrict__ tab) {
    int a = blockIdx.x * blockDim.x + threadIdx.x;
    if (a < N_ANG) {
        double th = M_PI * (double)a / 360.0;
        double c = cos(th), sn = sin(th);
        tab[a].c = c; tab[a].sn = sn;
        tab[a].cf = (float)c; tab[a].snf = (float)sn;
    }
}

// All four blurs in one launch: m = blockIdx.y in {img_b0, att_b0, img_b1, att_b1}.
// Unified r=4 window; image maps use a zero-padded 5-tap weight vector
// (reflect indexing identical to the r=2 pad since refl() is the same map).
__global__ void blur4_k(const float* __restrict__ img, const float* __restrict__ att,
                        float* __restrict__ pk, W9 wi, W9 wa) {
    int x = threadIdx.x, y = blockIdx.x, m = blockIdx.y;
    const float* src = ((m & 1) ? att : img) + (m >> 1) * IMG * IMG;
    const float* w = (m & 1) ? wa.w : wi.w;
    float scale = (m & 1) ? 0.01f : 1.0f;
    float acc = 0.f;
    for (int dy = -4; dy <= 4; ++dy) {
        float wy = w[dy + 4];
        if (wy == 0.f) continue;
        const float* rowp = src + refl(y + dy, IMG) * IMG;
        float ra = 0.f;
        for (int dx = -4; dx <= 4; ++dx) ra += w[dx + 4] * rowp[refl(x + dx, IMG)];
        acc += wy * ra;
    }
    pk[(y * IMG + x) * 4 + m] = acc * scale;
}

// Merged projection. H blocks (lanes = detectors) first, V blocks (lanes =
// samples) backfill. Fast f32 validity with EPS margin; rare exact-f64
// fallback reproduces numpy's per-op rounding bit-exactly.
__global__ __launch_bounds__(512) void proj_k(const float4* __restrict__ pk,
                                              const AngTab* __restrict__ tab,
                                              float4* __restrict__ part4) {
    int t = threadIdx.x;
    int bx = blockIdx.x;

    if (bx < NH_BLOCKS) {
        // ---- H-mode: |sin| <= |cos| (a in [0,90] U [270,359]) ----
        int d = t & 255, kc = t >> 8;
        int aidx = bx % 181, kt = bx / 181;
        int a = (aidx <= 90) ? aidx : aidx + 179;
        AngTab tb = tab[a];
        float cf = tb.cf, snf = tb.snf;
        float df = (float)d - 127.5f;
        float hx = fmaf(df, cf, 127.5f);
        float hy = fmaf(df, snf, 127.5f);
        int k0 = kt * 128 + kc * 64;

        float4 acc = make_float4(0.f, 0.f, 0.f, 0.f);
        for (int j = 0; j < 64; ++j) {
            int k = k0 + j;
            float kf = (float)k - 127.5f;
            float ixf = fmaf(-kf, snf, hx);
            float iyf = fmaf(kf, cf, hy);
            float vmin = fminf(fminf(ixf, 255.0f - ixf), fminf(iyf, 255.0f - iyf));
            if (!__any(vmin > -EPS)) continue;          // whole wave definitely out
            float m = (vmin >= EPS) ? 2.0f : 0.0f;      // valid * VOX
            if (fabsf(vmin) < EPS) {                    // rare exact check
                double ss = (double)(2 * k - 255);
                double rr = (double)(2 * d - 255);
                double rc = __dmul_rn(rr, tb.c), rs = __dmul_rn(rr, tb.sn);
                double ixd = __dadd_rn(__dmul_rn(__dsub_rn(rc, __dmul_rn(ss, tb.sn)), 0.5), 127.5);
                double iyd = __dadd_rn(__dmul_rn(__dadd_rn(rs, __dmul_rn(ss, tb.c)), 0.5), 127.5);
                bool v = (ixd >= 0.0) && (ixd <= 255.0) && (iyd >= 0.0) && (iyd <= 255.0);
                m = v ? 2.0f : 0.0f;
            }
            int j0 = (int)ixf; j0 = min(max(j0, 0), 254);
            int i0 = (int)iyf; i0 = min(max(i0, 0), 254);
            float fx = ixf - (float)j0;
            float fy = iyf - (float)i0;
            float gx = (1.f - fx) * m, fxm = fx * m;
            float gy = 1.f - fy;
            float w00 = gy * gx, w01 = gy * fxm, w10 = fy * gx, w11 = fy * fxm;
            const float4* p = pk + (i0 << 8) + j0;
            float4 t00 = p[0], t01 = p[1], t10 = p[IMG], t11 = p[IMG + 1];
            acc.x += w00 * t00.x + w01 * t01.x + w10 * t10.x + w11 * t11.x;
            acc.y += w00 * t00.y + w01 * t01.y + w10 * t10.y + w11 * t11.y;
            acc.z += w00 * t00.z + w01 * t01.z + w10 * t10.z + w11 * t11.z;
            acc.w += w00 * t00.w + w01 * t01.w + w10 * t10.w + w11 * t11.w;
        }

        __shared__ float4 red[512];
        red[t] = acc;
        __syncthreads();
        if (t < 256) {
            float4 u = red[t], v = red[t + 256];
            u.x += v.x; u.y += v.y; u.z += v.z; u.w += v.w;
            part4[(kt * N_ANG + a) * N_DET + t] = u;
        }
    } else {
        // ---- V-mode: |sin| > |cos| (a in [91,269]); lane = sample k ----
        int idx = bx - NH_BLOCKS;
        int a = 91 + (idx >> 5);
        int dgrp = idx & 31;
        int lane = t & 63, w = t >> 6;
        int d = dgrp * 8 + w;
        AngTab tb = tab[a];
        float cf = tb.cf, snf = tb.snf;
        float df = (float)d - 127.5f;
        float hx = fmaf(df, cf, 127.5f);
        float hy = fmaf(df, snf, 127.5f);

        float4 acc = make_float4(0.f, 0.f, 0.f, 0.f);
        #pragma unroll
        for (int j = 0; j < 4; ++j) {
            int k = j * 64 + lane;
            float kf = (float)k - 127.5f;
            float ixf = fmaf(-kf, snf, hx);
            float iyf = fmaf(kf, cf, hy);
            float vmin = fminf(fminf(ixf, 255.0f - ixf), fminf(iyf, 255.0f - iyf));
            if (!__any(vmin > -EPS)) continue;
            float m = (vmin >= EPS) ? 2.0f : 0.0f;
            if (fabsf(vmin) < EPS) {
                double ss = (double)(2 * k - 255);
                double rr = (double)(2 * d - 255);
                double rc = __dmul_rn(rr, tb.c), rs = __dmul_rn(rr, tb.sn);
                double ixd = __dadd_rn(__dmul_rn(__dsub_rn(rc, __dmul_rn(ss, tb.sn)), 0.5), 127.5);
                double iyd = __dadd_rn(__dmul_rn(__dadd_rn(rs, __dmul_rn(ss, tb.c)), 0.5), 127.5);
                bool v = (ixd >= 0.0) && (ixd <= 255.0) && (iyd >= 0.0) && (iyd <= 255.0);
                m = v ? 2.0f : 0.0f;
            }
            int j0 = (int)ixf; j0 = min(max(j0, 0), 254);
            int i0 = (int)iyf; i0 = min(max(i0, 0), 254);
            float fx = ixf - (float)j0;
            float fy = iyf - (float)i0;
            float gx = (1.f - fx) * m, fxm = fx * m;
            float gy = 1.f - fy;
            float w00 = gy * gx, w01 = gy * fxm, w10 = fy * gx, w11 = fy * fxm;
            const float4* p = pk + (i0 << 8) + j0;
            float4 t00 = p[0], t01 = p[1], t10 = p[IMG], t11 = p[IMG + 1];
            acc.x += w00 * t00.x + w01 * t01.x + w10 * t10.x + w11 * t11.x;
            acc.y += w00 * t00.y + w01 * t01.y + w10 * t10.y + w11 * t11.y;
            acc.z += w00 * t00.z + w01 * t01.z + w10 * t10.z + w11 * t11.z;
            acc.w += w00 * t00.w + w01 * t01.w + w10 * t10.w + w11 * t11.w;
        }

        #pragma unroll
        for (int off = 32; off; off >>= 1) {
            acc.x += __shfl_xor(acc.x, off);
            acc.y += __shfl_xor(acc.y, off);
            acc.z += __shfl_xor(acc.z, off);
            acc.w += __shfl_xor(acc.w, off);
        }
        if (lane == 0) {
            int o = a * N_DET + d;
            part4[o] = acc;                                             // kt=0
            part4[N_ANG * N_DET + o] = make_float4(0.f, 0.f, 0.f, 0.f); // kt=1
        }
    }
}

// kt-sum + attenuation + detector-axis blur + transpose to out[b][det][ang].
__global__ __launch_bounds__(256) void finish_k(const float4* __restrict__ part4,
                                                float* __restrict__ out, W9 wt) {
    int d = threadIdx.x;
    int ba = blockIdx.x;
    int b = ba / N_ANG, a = ba % N_ANG;
    float4 s = make_float4(0.f, 0.f, 0.f, 0.f);
    #pragma unroll
    for (int kt = 0; kt < 2; ++kt) {
        float4 q = part4[(kt * N_ANG + a) * N_DET + d];
        s.x += q.x; s.y += q.y; s.z += q.z; s.w += q.w;
    }
    float si = b ? s.z : s.x;
    float sa = b ? s.w : s.y;
    __shared__ float vb[N_DET];
    vb[d] = si * expf(-sa * 2.0f);
    __syncthreads();
    float acc = 0.f;
    #pragma unroll
    for (int i = -2; i <= 2; ++i) acc += wt.w[i + 2] * vb[refl(d + i, N_DET)];
    out[(b * N_DET + d) * N_ANG + a] = acc;
}

static void gauss_w(W9* wt, double sigma, int r, int pad_to_center4) {
    double tmp[9];
    double s = 0.0;
    for (int i = -r; i <= r; ++i) {
        double v = exp(-0.5 * ((double)i / sigma) * ((double)i / sigma));
        tmp[i + r] = v;
        s += v;
    }
    for (int i = 0; i < 9; ++i) wt->w[i] = 0.f;
    int off = pad_to_center4 ? (4 - r) : 0;
    for (int i = 0; i < 2 * r + 1; ++i) wt->w[i + off] = (float)(tmp[i] / s);
}

extern "C" void kernel_launch(void* const* d_in, const int* in_sizes, int n_in,
                              void* d_out, int out_size, void* d_ws, size_t ws_size,
                              hipStream_t stream) {
    const float* img = (const float*)d_in[0];
    const float* att = (const float*)d_in[1];
    float* out = (float*)d_out;

    char* ws = (char*)d_ws;
    AngTab* tab = (AngTab*)ws;                                // 360*32 B, pad to 16 KiB
    float* pk = (float*)(ws + 16384);                         // 256*256 float4 = 1 MiB
    float4* part4 = (float4*)(ws + 16384 + (1 << 20));        // 2*360*256*16 = 2.95 MiB

    double sqrt_log2 = sqrt(log(2.0));
    double sigma_img = 4.0 / (4.0 * sqrt_log2) / 2.0;         // ~0.60056, r=2
    double sigma_att = 4.0 / (2.0 * sqrt_log2) / 2.0;         // ~1.20112, r=4
    W9 wimg_pad, wimg, watt;
    gauss_w(&wimg_pad, sigma_img, 2, 1);   // 5-tap centered in 9 (for blur4_k)
    gauss_w(&wimg, sigma_img, 2, 0);       // 5-tap at [0..4] (for finish_k)
    gauss_w(&watt, sigma_att, 4, 0);

    tables_k<<<6, 64, 0, stream>>>(tab);
    blur4_k<<<dim3(IMG, 4), IMG, 0, stream>>>(img, att, pk, wimg_pad, watt);
    proj_k<<<NH_BLOCKS + NV_BLOCKS, 512, 0, stream>>>((const float4*)pk, tab, part4);
    finish_k<<<2 * N_ANG, N_DET, 0, stream>>>(part4, out, wimg);
}

// Round 6
// 69.900 us; speedup vs baseline: 4.3618x; 1.2103x over previous
//
#include <hip/hip_runtime.h>
#include <math.h>

#define IMG 256
#define N_ANG 360
#define N_DET 256
// VOX = 2.0

#define NH_BLOCKS 362              // 181 H-angles x 2 k-tiles
#define NV_BLOCKS (179 * 32)       // 179 V-angles x 32 detector-groups
#define EPS 1e-3f                  // f32-vs-f64 geometry margin (bound ~6e-5)

struct W9 { float w[9]; };
struct AngTab { double c, sn; float cf, snf; float pad0, pad1; };   // 32 B

typedef _Float16 h2 __attribute__((ext_vector_type(2)));

#if __has_builtin(__builtin_amdgcn_fdot2)
__device__ __forceinline__ float fdot2(h2 a, h2 b, float c) {
    return __builtin_amdgcn_fdot2(a, b, c, false);
}
#else
__device__ __forceinline__ float fdot2(h2 a, h2 b, float c) {
    return c + (float)a[0] * (float)b[0] + (float)a[1] * (float)b[1];
}
#endif

__device__ __forceinline__ h2 as_h2(unsigned u) { return __builtin_bit_cast(h2, u); }
__device__ __forceinline__ unsigned pack2(float a, float b) {
    h2 v = { (_Float16)a, (_Float16)b };        // RTN casts (unbiased)
    return __builtin_bit_cast(unsigned, v);
}

__device__ __forceinline__ int refl(int i, int L) {
    if (i < 0) i = -i;
    if (i >= L) i = 2 * (L - 1) - i;
    return i;
}

// Per-angle sin/cos table (f64 for exact fallback, f32 for the fast path).
__global__ void tables_k(AngTab* __restrict__ tab) {
    int a = blockIdx.x * blockDim.x + threadIdx.x;
    if (a < N_ANG) {
        double th = M_PI * (double)a / 360.0;
        double c = cos(th), sn = sin(th);
        tab[a].c = c; tab[a].sn = sn;
        tab[a].cf = (float)c; tab[a].snf = (float)sn;
    }
}

// All four blurs in one launch: m = blockIdx.y in {img_b0, att_b0, img_b1, att_b1}.
__global__ void blur4_k(const float* __restrict__ img, const float* __restrict__ att,
                        float* __restrict__ pk, W9 wi, W9 wa) {
    int x = threadIdx.x, y = blockIdx.x, m = blockIdx.y;
    const float* src = ((m & 1) ? att : img) + (m >> 1) * IMG * IMG;
    const float* w = (m & 1) ? wa.w : wi.w;
    float scale = (m & 1) ? 0.01f : 1.0f;
    float acc = 0.f;
    for (int dy = -4; dy <= 4; ++dy) {
        float wy = w[dy + 4];
        if (wy == 0.f) continue;
        const float* rowp = src + refl(y + dy, IMG) * IMG;
        float ra = 0.f;
        for (int dx = -4; dx <= 4; ++dx) ra += w[dx + 4] * rowp[refl(x + dx, IMG)];
        acc += wy * ra;
    }
    pk[(y * IMG + x) * 4 + m] = acc * scale;
}

// Redundant 2x2-quad f16 image: for each pixel (i,j), the 4 bilinear taps of
// all 4 maps packed into 32 contiguous bytes:
//   dwords: [m0 top(t00,t01), m0 bot(t10,t11), m1 top, m1 bot, m2.., m3..]
__global__ void quad_k(const float4* __restrict__ pk, uint4* __restrict__ quad) {
    int j = threadIdx.x, i = blockIdx.x;
    int jn = min(j + 1, IMG - 1), in_ = min(i + 1, IMG - 1);
    float4 p00 = pk[i * IMG + j],   p01 = pk[i * IMG + jn];
    float4 p10 = pk[in_ * IMG + j], p11 = pk[in_ * IMG + jn];
    uint4 qa, qb;
    qa.x = pack2(p00.x, p01.x); qa.y = pack2(p10.x, p11.x);
    qa.z = pack2(p00.y, p01.y); qa.w = pack2(p10.y, p11.y);
    qb.x = pack2(p00.z, p01.z); qb.y = pack2(p10.z, p11.z);
    qb.z = pack2(p00.w, p01.w); qb.w = pack2(p10.w, p11.w);
    int p = i * IMG + j;
    quad[2 * p] = qa;
    quad[2 * p + 1] = qb;
}

// One 32B quad read + 8 dot2 per sample (covers 2 batches x 2 maps).
__device__ __forceinline__ void tap_acc(const uint4* __restrict__ quad,
                                        int i0, int j0,
                                        float w00, float w01, float w10, float w11,
                                        float4& acc) {
    h2 wt = { (_Float16)w00, (_Float16)w01 };
    h2 wb = { (_Float16)w10, (_Float16)w11 };
    const uint4* q = quad + 2 * ((i0 << 8) + j0);
    uint4 qa = q[0], qb = q[1];
    acc.x = fdot2(as_h2(qa.x), wt, acc.x);
    acc.x = fdot2(as_h2(qa.y), wb, acc.x);
    acc.y = fdot2(as_h2(qa.z), wt, acc.y);
    acc.y = fdot2(as_h2(qa.w), wb, acc.y);
    acc.z = fdot2(as_h2(qb.x), wt, acc.z);
    acc.z = fdot2(as_h2(qb.y), wb, acc.z);
    acc.w = fdot2(as_h2(qb.z), wt, acc.w);
    acc.w = fdot2(as_h2(qb.w), wb, acc.w);
}

// Merged projection. H blocks (lanes = detectors) first, V blocks (lanes =
// samples) backfill. Fast f32 validity with EPS margin; rare exact-f64
// fallback reproduces numpy's per-op rounding bit-exactly.
__global__ __launch_bounds__(512) void proj_k(const uint4* __restrict__ quad,
                                              const AngTab* __restrict__ tab,
                                              float4* __restrict__ part4) {
    int t = threadIdx.x;
    int bx = blockIdx.x;

    if (bx < NH_BLOCKS) {
        // ---- H-mode: |sin| <= |cos| (a in [0,90] U [270,359]) ----
        int d = t & 255, kc = t >> 8;
        int aidx = bx % 181, kt = bx / 181;
        int a = (aidx <= 90) ? aidx : aidx + 179;
        AngTab tb = tab[a];
        float cf = tb.cf, snf = tb.snf;
        float df = (float)d - 127.5f;
        float hx = fmaf(df, cf, 127.5f);
        float hy = fmaf(df, snf, 127.5f);
        int k0 = kt * 128 + kc * 64;

        float4 acc = make_float4(0.f, 0.f, 0.f, 0.f);
        for (int j = 0; j < 64; ++j) {
            int k = k0 + j;
            float kf = (float)k - 127.5f;
            float ixf = fmaf(-kf, snf, hx);
            float iyf = fmaf(kf, cf, hy);
            float vmin = fminf(fminf(ixf, 255.0f - ixf), fminf(iyf, 255.0f - iyf));
            if (!__any(vmin > -EPS)) continue;          // whole wave definitely out
            float m = (vmin >= EPS) ? 2.0f : 0.0f;      // valid * VOX
            if (fabsf(vmin) < EPS) {                    // rare exact check
                double ss = (double)(2 * k - 255);
                double rr = (double)(2 * d - 255);
                double rc = __dmul_rn(rr, tb.c), rs = __dmul_rn(rr, tb.sn);
                double ixd = __dadd_rn(__dmul_rn(__dsub_rn(rc, __dmul_rn(ss, tb.sn)), 0.5), 127.5);
                double iyd = __dadd_rn(__dmul_rn(__dadd_rn(rs, __dmul_rn(ss, tb.c)), 0.5), 127.5);
                bool v = (ixd >= 0.0) && (ixd <= 255.0) && (iyd >= 0.0) && (iyd <= 255.0);
                m = v ? 2.0f : 0.0f;
            }
            int j0 = (int)ixf; j0 = min(max(j0, 0), 254);
            int i0 = (int)iyf; i0 = min(max(i0, 0), 254);
            float fx = ixf - (float)j0;
            float fy = iyf - (float)i0;
            float gxm = (1.f - fx) * m, fxm = fx * m;
            float gy = 1.f - fy;
            tap_acc(quad, i0, j0, gy * gxm, gy * fxm, fy * gxm, fy * fxm, acc);
        }

        __shared__ float4 red[512];
        red[t] = acc;
        __syncthreads();
        if (t < 256) {
            float4 u = red[t], v = red[t + 256];
            u.x += v.x; u.y += v.y; u.z += v.z; u.w += v.w;
            part4[(kt * N_ANG + a) * N_DET + t] = u;
        }
    } else {
        // ---- V-mode: |sin| > |cos| (a in [91,269]); lane = sample k ----
        int idx = bx - NH_BLOCKS;
        int a = 91 + (idx >> 5);
        int dgrp = idx & 31;
        int lane = t & 63, w = t >> 6;
        int d = dgrp * 8 + w;
        AngTab tb = tab[a];
        float cf = tb.cf, snf = tb.snf;
        float df = (float)d - 127.5f;
        float hx = fmaf(df, cf, 127.5f);
        float hy = fmaf(df, snf, 127.5f);

        float4 acc = make_float4(0.f, 0.f, 0.f, 0.f);
        #pragma unroll
        for (int j = 0; j < 4; ++j) {
            int k = j * 64 + lane;
            float kf = (float)k - 127.5f;
            float ixf = fmaf(-kf, snf, hx);
            float iyf = fmaf(kf, cf, hy);
            float vmin = fminf(fminf(ixf, 255.0f - ixf), fminf(iyf, 255.0f - iyf));
            if (!__any(vmin > -EPS)) continue;
            float m = (vmin >= EPS) ? 2.0f : 0.0f;
            if (fabsf(vmin) < EPS) {
                double ss = (double)(2 * k - 255);
                double rr = (double)(2 * d - 255);
                double rc = __dmul_rn(rr, tb.c), rs = __dmul_rn(rr, tb.sn);
                double ixd = __dadd_rn(__dmul_rn(__dsub_rn(rc, __dmul_rn(ss, tb.sn)), 0.5), 127.5);
                double iyd = __dadd_rn(__dmul_rn(__dadd_rn(rs, __dmul_rn(ss, tb.c)), 0.5), 127.5);
                bool v = (ixd >= 0.0) && (ixd <= 255.0) && (iyd >= 0.0) && (iyd <= 255.0);
                m = v ? 2.0f : 0.0f;
            }
            int j0 = (int)ixf; j0 = min(max(j0, 0), 254);
            int i0 = (int)iyf; i0 = min(max(i0, 0), 254);
            float fx = ixf - (float)j0;
            float fy = iyf - (float)i0;
            float gxm = (1.f - fx) * m, fxm = fx * m;
            float gy = 1.f - fy;
            tap_acc(quad, i0, j0, gy * gxm, gy * fxm, fy * gxm, fy * fxm, acc);
        }

        #pragma unroll
        for (int off = 32; off; off >>= 1) {
            acc.x += __shfl_xor(acc.x, off);
            acc.y += __shfl_xor(acc.y, off);
            acc.z += __shfl_xor(acc.z, off);
            acc.w += __shfl_xor(acc.w, off);
        }
        if (lane == 0) {
            int o = a * N_DET + d;
            part4[o] = acc;                                             // kt=0
            part4[N_ANG * N_DET + o] = make_float4(0.f, 0.f, 0.f, 0.f); // kt=1
        }
    }
}

// kt-sum + attenuation + detector-axis blur + transpose to out[b][det][ang].
__global__ __launch_bounds__(256) void finish_k(const float4* __restrict__ part4,
                                                float* __restrict__ out, W9 wt) {
    int d = threadIdx.x;
    int ba = blockIdx.x;
    int b = ba / N_ANG, a = ba % N_ANG;
    float4 s = make_float4(0.f, 0.f, 0.f, 0.f);
    #pragma unroll
    for (int kt = 0; kt < 2; ++kt) {
        float4 q = part4[(kt * N_ANG + a) * N_DET + d];
        s.x += q.x; s.y += q.y; s.z += q.z; s.w += q.w;
    }
    float si = b ? s.z : s.x;
    float sa = b ? s.w : s.y;
    __shared__ float vb[N_DET];
    vb[d] = si * expf(-sa * 2.0f);
    __syncthreads();
    float acc = 0.f;
    #pragma unroll
    for (int i = -2; i <= 2; ++i) acc += wt.w[i + 2] * vb[refl(d + i, N_DET)];
    out[(b * N_DET + d) * N_ANG + a] = acc;
}

static void gauss_w(W9* wt, double sigma, int r, int pad_to_center4) {
    double tmp[9];
    double s = 0.0;
    for (int i = -r; i <= r; ++i) {
        double v = exp(-0.5 * ((double)i / sigma) * ((double)i / sigma));
        tmp[i + r] = v;
        s += v;
    }
    for (int i = 0; i < 9; ++i) wt->w[i] = 0.f;
    int off = pad_to_center4 ? (4 - r) : 0;
    for (int i = 0; i < 2 * r + 1; ++i) wt->w[i + off] = (float)(tmp[i] / s);
}

extern "C" void kernel_launch(void* const* d_in, const int* in_sizes, int n_in,
                              void* d_out, int out_size, void* d_ws, size_t ws_size,
                              hipStream_t stream) {
    const float* img = (const float*)d_in[0];
    const float* att = (const float*)d_in[1];
    float* out = (float*)d_out;

    char* ws = (char*)d_ws;
    AngTab* tab = (AngTab*)ws;                                  // 16 KiB slot
    float* pk = (float*)(ws + 16384);                           // 1 MiB (f32 float4)
    uint4* quad = (uint4*)(ws + 16384 + (1 << 20));             // 2 MiB (f16 quads)
    float4* part4 = (float4*)(ws + 16384 + 3 * (1 << 20));      // 2.95 MiB

    double sqrt_log2 = sqrt(log(2.0));
    double sigma_img = 4.0 / (4.0 * sqrt_log2) / 2.0;           // ~0.60056, r=2
    double sigma_att = 4.0 / (2.0 * sqrt_log2) / 2.0;           // ~1.20112, r=4
    W9 wimg_pad, wimg, watt;
    gauss_w(&wimg_pad, sigma_img, 2, 1);   // 5-tap centered in 9 (for blur4_k)
    gauss_w(&wimg, sigma_img, 2, 0);       // 5-tap at [0..4] (for finish_k)
    gauss_w(&watt, sigma_att, 4, 0);

    tables_k<<<6, 64, 0, stream>>>(tab);
    blur4_k<<<dim3(IMG, 4), IMG, 0, stream>>>(img, att, pk, wimg_pad, watt);
    quad_k<<<IMG, IMG, 0, stream>>>((const float4*)pk, quad);
    proj_k<<<NH_BLOCKS + NV_BLOCKS, 512, 0, stream>>>(quad, tab, part4);
    finish_k<<<2 * N_ANG, N_DET, 0, stream>>>(part4, out, wimg);
}

// Round 7
// 67.628 us; speedup vs baseline: 4.5083x; 1.0336x over previous
//
#include <hip/hip_runtime.h>
#include <math.h>

#define IMG 256
#define N_ANG 360
#define N_DET 256
// VOX = 2.0

#define NH_BLOCKS 181              // 181 H-angles (kt merged)
#define NV_BLOCKS (179 * 32)       // 179 V-angles x 32 detector-groups
#define EPS 1e-3f                  // f32-vs-f64 geometry margin (V-mode only)

struct W9 { float w[9]; };
struct AngTab { double c, sn; float cf, snf; float pad0, pad1; };   // 32 B

typedef _Float16 h2 __attribute__((ext_vector_type(2)));

#if __has_builtin(__builtin_amdgcn_fdot2)
__device__ __forceinline__ float fdot2(h2 a, h2 b, float c) {
    return __builtin_amdgcn_fdot2(a, b, c, false);
}
#else
__device__ __forceinline__ float fdot2(h2 a, h2 b, float c) {
    return c + (float)a[0] * (float)b[0] + (float)a[1] * (float)b[1];
}
#endif

__device__ __forceinline__ h2 as_h2(unsigned u) { return __builtin_bit_cast(h2, u); }
__device__ __forceinline__ unsigned pack2(float a, float b) {
    h2 v = { (_Float16)a, (_Float16)b };        // RTN casts (unbiased)
    return __builtin_bit_cast(unsigned, v);
}

__device__ __forceinline__ int refl(int i, int L) {
    if (i < 0) i = -i;
    if (i >= L) i = 2 * (L - 1) - i;
    return i;
}

// All four blurs in one launch: m = blockIdx.y in {img_b0, att_b0, img_b1, att_b1}.
__global__ void blur4_k(const float* __restrict__ img, const float* __restrict__ att,
                        float* __restrict__ pk, W9 wi, W9 wa) {
    int x = threadIdx.x, y = blockIdx.x, m = blockIdx.y;
    const float* src = ((m & 1) ? att : img) + (m >> 1) * IMG * IMG;
    const float* w = (m & 1) ? wa.w : wi.w;
    float scale = (m & 1) ? 0.01f : 1.0f;
    float acc = 0.f;
    for (int dy = -4; dy <= 4; ++dy) {
        float wy = w[dy + 4];
        if (wy == 0.f) continue;
        const float* rowp = src + refl(y + dy, IMG) * IMG;
        float ra = 0.f;
        for (int dx = -4; dx <= 4; ++dx) ra += w[dx + 4] * rowp[refl(x + dx, IMG)];
        acc += wy * ra;
    }
    pk[(y * IMG + x) * 4 + m] = acc * scale;
}

// Quad pack + (first 360 threads) per-angle sin/cos tables.
__global__ void quad_k(const float4* __restrict__ pk, uint4* __restrict__ quad,
                       AngTab* __restrict__ tab) {
    int j = threadIdx.x, i = blockIdx.x;
    int gid = i * IMG + j;
    if (gid < N_ANG) {
        double th = M_PI * (double)gid / 360.0;
        double c = cos(th), sn = sin(th);
        AngTab tb;
        tb.c = c; tb.sn = sn; tb.cf = (float)c; tb.snf = (float)sn;
        tb.pad0 = 0.f; tb.pad1 = 0.f;
        tab[gid] = tb;
    }
    int jn = min(j + 1, IMG - 1), in_ = min(i + 1, IMG - 1);
    float4 p00 = pk[i * IMG + j],   p01 = pk[i * IMG + jn];
    float4 p10 = pk[in_ * IMG + j], p11 = pk[in_ * IMG + jn];
    uint4 qa, qb;
    qa.x = pack2(p00.x, p01.x); qa.y = pack2(p10.x, p11.x);
    qa.z = pack2(p00.y, p01.y); qa.w = pack2(p10.y, p11.y);
    qb.x = pack2(p00.z, p01.z); qb.y = pack2(p10.z, p11.z);
    qb.z = pack2(p00.w, p01.w); qb.w = pack2(p10.w, p11.w);
    int p = i * IMG + j;
    quad[2 * p] = qa;
    quad[2 * p + 1] = qb;
}

template <typename P>
__device__ __forceinline__ int lastTrue(P p) {     // pred true-set is a prefix of [0,255]
    if (!p(0)) return -1;
    if (p(255)) return 255;
    int lo = 0, hi = 255;
    while (lo < hi) { int m = (lo + hi + 1) >> 1; if (p(m)) lo = m; else hi = m - 1; }
    return lo;
}
template <typename P>
__device__ __forceinline__ int firstTrue(P p) {    // pred true-set is a suffix of [0,255]
    if (!p(255)) return 256;
    if (p(0)) return 0;
    int lo = 0, hi = 255;
    while (lo < hi) { int m = (lo + hi) >> 1; if (p(m)) hi = m; else lo = m + 1; }
    return lo;
}

// One 32B quad read + 8 dot2 per sample (covers 2 batches x 2 maps).
__device__ __forceinline__ void tap_acc(const uint4* __restrict__ quad,
                                        int i0, int j0,
                                        float w00, float w01, float w10, float w11,
                                        float4& acc) {
    h2 wt = { (_Float16)w00, (_Float16)w01 };
    h2 wb = { (_Float16)w10, (_Float16)w11 };
    const uint4* q = quad + 2 * ((i0 << 8) + j0);
    uint4 qa = q[0], qb = q[1];
    acc.x = fdot2(as_h2(qa.x), wt, acc.x);
    acc.x = fdot2(as_h2(qa.y), wb, acc.x);
    acc.y = fdot2(as_h2(qa.z), wt, acc.y);
    acc.y = fdot2(as_h2(qa.w), wb, acc.y);
    acc.z = fdot2(as_h2(qb.x), wt, acc.z);
    acc.z = fdot2(as_h2(qb.y), wb, acc.z);
    acc.w = fdot2(as_h2(qb.z), wt, acc.w);
    acc.w = fdot2(as_h2(qb.w), wb, acc.w);
}

// Merged projection. 181 H blocks (lanes = detectors, exact per-ray interval,
// inline finish) + 5728 V blocks (lanes = samples, per-sample EPS+f64 check).
__global__ __launch_bounds__(512) void proj_k(const uint4* __restrict__ quad,
                                              const AngTab* __restrict__ tab,
                                              float4* __restrict__ part4,
                                              float* __restrict__ out, W9 wblur) {
    int t = threadIdx.x;
    int bx = blockIdx.x;

    if (bx < NH_BLOCKS) {
        // ---- H-mode: |sin| <= |cos| (a in [0,90] U [270,359]) ----
        int d = t & 255, kc = t >> 8;
        int a = (bx <= 90) ? bx : bx + 179;
        AngTab tb = tab[a];
        double rr = (double)(2 * d - 255);
        double rc = __dmul_rn(rr, tb.c), rs = __dmul_rn(rr, tb.sn);

        auto evIx = [&](int k) -> double {
            double ss = (double)(2 * k - 255);
            return __dadd_rn(__dmul_rn(__dsub_rn(rc, __dmul_rn(ss, tb.sn)), 0.5), 127.5);
        };
        auto evIy = [&](int k) -> double {
            double ss = (double)(2 * k - 255);
            return __dadd_rn(__dmul_rn(__dadd_rn(rs, __dmul_rn(ss, tb.c)), 0.5), 127.5);
        };
        // ix non-increasing in k (slope -sn, sn>=0 for all a); iy slope = +c.
        int khiA = lastTrue([&](int k) { return evIx(k) >= 0.0; });
        int kloA = firstTrue([&](int k) { return evIx(k) <= 255.0; });
        int kloB, khiB;
        if (tb.c > 0.0) {
            kloB = firstTrue([&](int k) { return evIy(k) >= 0.0; });
            khiB = lastTrue([&](int k) { return evIy(k) <= 255.0; });
        } else {
            khiB = lastTrue([&](int k) { return evIy(k) >= 0.0; });
            kloB = firstTrue([&](int k) { return evIy(k) <= 255.0; });
        }
        int lo = max(kloA, kloB), hi = min(khiA, khiB);
        lo = max(lo, kc * 128); hi = min(hi, kc * 128 + 127);   // this thread's chunk
        if (lo > hi) { lo = 0; hi = -1; }                        // canonical empty

        // wave hull + wave-interior range
        int jl = (hi >= lo) ? lo : 0x7fffffff;
        int jh = (hi >= lo) ? hi : (-0x7fffffff - 1);
        int en = lo, ex = hi;    // interior needs ALL lanes valid (empty lane: en=0,ex=-1 kills it)
        #pragma unroll
        for (int off = 32; off; off >>= 1) {
            jl = min(jl, __shfl_xor(jl, off));
            jh = max(jh, __shfl_xor(jh, off));
            en = max(en, __shfl_xor(en, off));
            ex = min(ex, __shfl_xor(ex, off));
        }

        float x0f = (float)evIx(128);
        float y0f = (float)evIy(128);
        float dxf = -tb.snf, dyf = tb.cf;

        float4 acc = make_float4(0.f, 0.f, 0.f, 0.f);
        auto body = [&](int k, bool fast) {
            float kf = (float)(k - 128);
            float ixf = fmaf(kf, dxf, x0f);
            float iyf = fmaf(kf, dyf, y0f);
            float m = fast ? 2.0f : ((k >= lo && k <= hi) ? 2.0f : 0.0f);  // valid*VOX
            int j0 = (int)ixf; j0 = min(max(j0, 0), 254);
            int i0 = (int)iyf; i0 = min(max(i0, 0), 254);
            float fx = ixf - (float)j0;
            float fy = iyf - (float)i0;
            float gxm = (1.f - fx) * m, fxm = fx * m;
            float gy = 1.f - fy;
            tap_acc(quad, i0, j0, gy * gxm, gy * fxm, fy * gxm, fy * fxm, acc);
        };
        if (jl <= jh) {
            if (en <= ex) {
                for (int k = jl; k < en; ++k) body(k, false);
                for (int k = en; k <= ex; ++k) body(k, true);
                for (int k = ex + 1; k <= jh; ++k) body(k, false);
            } else {
                for (int k = jl; k <= jh; ++k) body(k, false);
            }
        }

        __shared__ float4 red[512];
        __shared__ float vb[2][N_DET];
        red[t] = acc;
        __syncthreads();
        if (t < 256) {
            float4 u = red[t], v = red[t + 256];
            float si0 = u.x + v.x, sa0 = u.y + v.y;
            float si1 = u.z + v.z, sa1 = u.w + v.w;
            vb[0][t] = si0 * expf(-sa0 * 2.0f);   // * exp(-att_sino * VOX)
            vb[1][t] = si1 * expf(-sa1 * 2.0f);
        }
        __syncthreads();
        if (t < 256) {
            float a0 = 0.f, a1 = 0.f;
            #pragma unroll
            for (int i = -2; i <= 2; ++i) {
                int dd = refl(t + i, N_DET);
                a0 += wblur.w[i + 2] * vb[0][dd];
                a1 += wblur.w[i + 2] * vb[1][dd];
            }
            out[t * N_ANG + a] = a0;                       // b=0
            out[(N_DET + t) * N_ANG + a] = a1;             // b=1
        }
    } else {
        // ---- V-mode: |sin| > |cos| (a in [91,269]); lane = sample k ----
        int idx = bx - NH_BLOCKS;
        int a = 91 + (idx >> 5);
        int dgrp = idx & 31;
        int lane = t & 63, w = t >> 6;
        int d = dgrp * 8 + w;
        AngTab tb = tab[a];
        float cf = tb.cf, snf = tb.snf;
        float df = (float)d - 127.5f;
        float hx = fmaf(df, cf, 127.5f);
        float hy = fmaf(df, snf, 127.5f);

        float4 acc = make_float4(0.f, 0.f, 0.f, 0.f);
        #pragma unroll
        for (int j = 0; j < 4; ++j) {
            int k = j * 64 + lane;
            float kf = (float)k - 127.5f;
            float ixf = fmaf(-kf, snf, hx);
            float iyf = fmaf(kf, cf, hy);
            float vmin = fminf(fminf(ixf, 255.0f - ixf), fminf(iyf, 255.0f - iyf));
            if (!__any(vmin > -EPS)) continue;
            float m = (vmin >= EPS) ? 2.0f : 0.0f;
            if (fabsf(vmin) < EPS) {                       // rare exact check
                double ss = (double)(2 * k - 255);
                double rr = (double)(2 * d - 255);
                double rc = __dmul_rn(rr, tb.c), rs = __dmul_rn(rr, tb.sn);
                double ixd = __dadd_rn(__dmul_rn(__dsub_rn(rc, __dmul_rn(ss, tb.sn)), 0.5), 127.5);
                double iyd = __dadd_rn(__dmul_rn(__dadd_rn(rs, __dmul_rn(ss, tb.c)), 0.5), 127.5);
                bool v = (ixd >= 0.0) && (ixd <= 255.0) && (iyd >= 0.0) && (iyd <= 255.0);
                m = v ? 2.0f : 0.0f;
            }
            int j0 = (int)ixf; j0 = min(max(j0, 0), 254);
            int i0 = (int)iyf; i0 = min(max(i0, 0), 254);
            float fx = ixf - (float)j0;
            float fy = iyf - (float)i0;
            float gxm = (1.f - fx) * m, fxm = fx * m;
            float gy = 1.f - fy;
            tap_acc(quad, i0, j0, gy * gxm, gy * fxm, fy * gxm, fy * fxm, acc);
        }

        #pragma unroll
        for (int off = 32; off; off >>= 1) {
            acc.x += __shfl_xor(acc.x, off);
            acc.y += __shfl_xor(acc.y, off);
            acc.z += __shfl_xor(acc.z, off);
            acc.w += __shfl_xor(acc.w, off);
        }
        if (lane == 0) part4[a * N_DET + d] = acc;
    }
}

// V-angles only: attenuation + detector-axis blur + transpose.
__global__ __launch_bounds__(256) void finish_v_k(const float4* __restrict__ part4,
                                                  float* __restrict__ out, W9 wt) {
    int d = threadIdx.x;
    int b = blockIdx.x / 179;
    int a = 91 + (blockIdx.x % 179);
    float4 s = part4[a * N_DET + d];
    float si = b ? s.z : s.x;
    float sa = b ? s.w : s.y;
    __shared__ float vb[N_DET];
    vb[d] = si * expf(-sa * 2.0f);
    __syncthreads();
    float acc = 0.f;
    #pragma unroll
    for (int i = -2; i <= 2; ++i) acc += wt.w[i + 2] * vb[refl(d + i, N_DET)];
    out[(b * N_DET + d) * N_ANG + a] = acc;
}

static void gauss_w(W9* wt, double sigma, int r, int pad_to_center4) {
    double tmp[9];
    double s = 0.0;
    for (int i = -r; i <= r; ++i) {
        double v = exp(-0.5 * ((double)i / sigma) * ((double)i / sigma));
        tmp[i + r] = v;
        s += v;
    }
    for (int i = 0; i < 9; ++i) wt->w[i] = 0.f;
    int off = pad_to_center4 ? (4 - r) : 0;
    for (int i = 0; i < 2 * r + 1; ++i) wt->w[i + off] = (float)(tmp[i] / s);
}

extern "C" void kernel_launch(void* const* d_in, const int* in_sizes, int n_in,
                              void* d_out, int out_size, void* d_ws, size_t ws_size,
                              hipStream_t stream) {
    const float* img = (const float*)d_in[0];
    const float* att = (const float*)d_in[1];
    float* out = (float*)d_out;

    char* ws = (char*)d_ws;
    AngTab* tab = (AngTab*)ws;                                  // 16 KiB slot
    float* pk = (float*)(ws + 16384);                           // 1 MiB (f32 float4)
    uint4* quad = (uint4*)(ws + 16384 + (1 << 20));             // 2 MiB (f16 quads)
    float4* part4 = (float4*)(ws + 16384 + 3 * (1 << 20));      // 1.47 MiB (V only)

    double sqrt_log2 = sqrt(log(2.0));
    double sigma_img = 4.0 / (4.0 * sqrt_log2) / 2.0;           // ~0.60056, r=2
    double sigma_att = 4.0 / (2.0 * sqrt_log2) / 2.0;           // ~1.20112, r=4
    W9 wimg_pad, wimg, watt;
    gauss_w(&wimg_pad, sigma_img, 2, 1);   // 5-tap centered in 9 (for blur4_k)
    gauss_w(&wimg, sigma_img, 2, 0);       // 5-tap at [0..4] (for finish)
    gauss_w(&watt, sigma_att, 4, 0);

    blur4_k<<<dim3(IMG, 4), IMG, 0, stream>>>(img, att, pk, wimg_pad, watt);
    quad_k<<<IMG, IMG, 0, stream>>>((const float4*)pk, quad, tab);
    proj_k<<<NH_BLOCKS + NV_BLOCKS, 512, 0, stream>>>(quad, tab, part4, out, wimg);
    finish_v_k<<<2 * 179, N_DET, 0, stream>>>(part4, out, wimg);
}

// Round 8
// 61.949 us; speedup vs baseline: 4.9215x; 1.0917x over previous
//
#include <hip/hip_runtime.h>
#include <math.h>

#define IMG 256
#define N_ANG 360
#define N_DET 256
// VOX = 2.0

#define NH_BLOCKS 181              // 181 H-angles (kt merged)
#define NV_BLOCKS (179 * 32)       // 179 V-angles x 32 detector-groups
#define EPS 1e-3f                  // f32-vs-f64 geometry margin (V-mode only)

struct W9 { float w[9]; };
struct AngTab { double c, sn; float cf, snf; float pad0, pad1; };   // 32 B

typedef _Float16 h2 __attribute__((ext_vector_type(2)));

#if __has_builtin(__builtin_amdgcn_fdot2)
__device__ __forceinline__ float fdot2(h2 a, h2 b, float c) {
    return __builtin_amdgcn_fdot2(a, b, c, false);
}
#else
__device__ __forceinline__ float fdot2(h2 a, h2 b, float c) {
    return c + (float)a[0] * (float)b[0] + (float)a[1] * (float)b[1];
}
#endif

__device__ __forceinline__ h2 as_h2(unsigned u) { return __builtin_bit_cast(h2, u); }
__device__ __forceinline__ unsigned pack2(float a, float b) {
    h2 v = { (_Float16)a, (_Float16)b };        // RTN casts (unbiased)
    return __builtin_bit_cast(unsigned, v);
}

__device__ __forceinline__ int refl(int i, int L) {
    if (i < 0) i = -i;
    if (i >= L) i = 2 * (L - 1) - i;
    return i;
}

// All four blurs in one launch: m = blockIdx.y in {img_b0, att_b0, img_b1, att_b1}.
__global__ void blur4_k(const float* __restrict__ img, const float* __restrict__ att,
                        float* __restrict__ pk, W9 wi, W9 wa) {
    int x = threadIdx.x, y = blockIdx.x, m = blockIdx.y;
    const float* src = ((m & 1) ? att : img) + (m >> 1) * IMG * IMG;
    const float* w = (m & 1) ? wa.w : wi.w;
    float scale = (m & 1) ? 0.01f : 1.0f;
    float acc = 0.f;
    for (int dy = -4; dy <= 4; ++dy) {
        float wy = w[dy + 4];
        if (wy == 0.f) continue;
        const float* rowp = src + refl(y + dy, IMG) * IMG;
        float ra = 0.f;
        for (int dx = -4; dx <= 4; ++dx) ra += w[dx + 4] * rowp[refl(x + dx, IMG)];
        acc += wy * ra;
    }
    pk[(y * IMG + x) * 4 + m] = acc * scale;
}

// Quad pack + (first 360 threads) per-angle sin/cos tables.
__global__ void quad_k(const float4* __restrict__ pk, uint4* __restrict__ quad,
                       AngTab* __restrict__ tab) {
    int j = threadIdx.x, i = blockIdx.x;
    int gid = i * IMG + j;
    if (gid < N_ANG) {
        double th = M_PI * (double)gid / 360.0;
        double c = cos(th), sn = sin(th);
        AngTab tb;
        tb.c = c; tb.sn = sn; tb.cf = (float)c; tb.snf = (float)sn;
        tb.pad0 = 0.f; tb.pad1 = 0.f;
        tab[gid] = tb;
    }
    int jn = min(j + 1, IMG - 1), in_ = min(i + 1, IMG - 1);
    float4 p00 = pk[i * IMG + j],   p01 = pk[i * IMG + jn];
    float4 p10 = pk[in_ * IMG + j], p11 = pk[in_ * IMG + jn];
    uint4 qa, qb;
    qa.x = pack2(p00.x, p01.x); qa.y = pack2(p10.x, p11.x);
    qa.z = pack2(p00.y, p01.y); qa.w = pack2(p10.y, p11.y);
    qb.x = pack2(p00.z, p01.z); qb.y = pack2(p10.z, p11.z);
    qb.z = pack2(p00.w, p01.w); qb.w = pack2(p10.w, p11.w);
    int p = i * IMG + j;
    quad[2 * p] = qa;
    quad[2 * p + 1] = qb;
}

template <typename P>
__device__ __forceinline__ int lastTrue(P p) {     // pred true-set is a prefix of [0,255]
    if (!p(0)) return -1;
    if (p(255)) return 255;
    int lo = 0, hi = 255;
    while (lo < hi) { int m = (lo + hi + 1) >> 1; if (p(m)) lo = m; else hi = m - 1; }
    return lo;
}
template <typename P>
__device__ __forceinline__ int firstTrue(P p) {    // pred true-set is a suffix of [0,255]
    if (!p(255)) return 256;
    if (p(0)) return 0;
    int lo = 0, hi = 255;
    while (lo < hi) { int m = (lo + hi) >> 1; if (p(m)) hi = m; else lo = m + 1; }
    return lo;
}

// One 32B quad read + 8 dot2 per sample (covers 2 batches x 2 maps).
__device__ __forceinline__ void tap_acc(const uint4* __restrict__ quad,
                                        int i0, int j0,
                                        float w00, float w01, float w10, float w11,
                                        float4& acc) {
    h2 wt = { (_Float16)w00, (_Float16)w01 };
    h2 wb = { (_Float16)w10, (_Float16)w11 };
    const uint4* q = quad + 2 * ((i0 << 8) + j0);
    uint4 qa = q[0], qb = q[1];
    acc.x = fdot2(as_h2(qa.x), wt, acc.x);
    acc.x = fdot2(as_h2(qa.y), wb, acc.x);
    acc.y = fdot2(as_h2(qa.z), wt, acc.y);
    acc.y = fdot2(as_h2(qa.w), wb, acc.y);
    acc.z = fdot2(as_h2(qb.x), wt, acc.z);
    acc.z = fdot2(as_h2(qb.y), wb, acc.z);
    acc.w = fdot2(as_h2(qb.z), wt, acc.w);
    acc.w = fdot2(as_h2(qb.w), wb, acc.w);
}

// Merged projection. 181 H blocks (lanes = detectors, exact per-ray interval,
// unroll-4 hull walk, inline finish) + 5728 V blocks (lanes = samples).
__global__ __launch_bounds__(512) void proj_k(const uint4* __restrict__ quad,
                                              const AngTab* __restrict__ tab,
                                              float4* __restrict__ part4,
                                              float* __restrict__ out, W9 wblur) {
    int t = threadIdx.x;
    int bx = blockIdx.x;

    if (bx < NH_BLOCKS) {
        // ---- H-mode: |sin| <= |cos| (a in [0,90] U [270,359]) ----
        int d = t & 255, kc = t >> 8;
        int a = (bx <= 90) ? bx : bx + 179;
        AngTab tb = tab[a];
        double rr = (double)(2 * d - 255);
        double rc = __dmul_rn(rr, tb.c), rs = __dmul_rn(rr, tb.sn);

        auto evIx = [&](int k) -> double {
            double ss = (double)(2 * k - 255);
            return __dadd_rn(__dmul_rn(__dsub_rn(rc, __dmul_rn(ss, tb.sn)), 0.5), 127.5);
        };
        auto evIy = [&](int k) -> double {
            double ss = (double)(2 * k - 255);
            return __dadd_rn(__dmul_rn(__dadd_rn(rs, __dmul_rn(ss, tb.c)), 0.5), 127.5);
        };
        // ix non-increasing in k (slope -sn, sn>=0 for all a); iy slope = +c.
        int khiA = lastTrue([&](int k) { return evIx(k) >= 0.0; });
        int kloA = firstTrue([&](int k) { return evIx(k) <= 255.0; });
        int kloB, khiB;
        if (tb.c > 0.0) {
            kloB = firstTrue([&](int k) { return evIy(k) >= 0.0; });
            khiB = lastTrue([&](int k) { return evIy(k) <= 255.0; });
        } else {
            khiB = lastTrue([&](int k) { return evIy(k) >= 0.0; });
            kloB = firstTrue([&](int k) { return evIy(k) <= 255.0; });
        }
        int lo = max(kloA, kloB), hi = min(khiA, khiB);
        lo = max(lo, kc * 128); hi = min(hi, kc * 128 + 127);   // this thread's chunk
        if (lo > hi) { lo = 0; hi = -1; }                        // canonical empty

        // wave hull
        int jl = (hi >= lo) ? lo : 0x7fffffff;
        int jh = (hi >= lo) ? hi : (-0x7fffffff - 1);
        #pragma unroll
        for (int off = 32; off; off >>= 1) {
            jl = min(jl, __shfl_xor(jl, off));
            jh = max(jh, __shfl_xor(jh, off));
        }

        float x0f = (float)evIx(128);
        float y0f = (float)evIy(128);
        float dxf = -tb.snf, dyf = tb.cf;

        float4 acc = make_float4(0.f, 0.f, 0.f, 0.f);
        // Unroll-4 hull walk: 4 independent samples per trip -> 8 gathers in
        // flight. Overshoot samples are mask-killed (addresses clamped).
        for (int kb = jl; kb <= jh; kb += 4) {
            #pragma unroll
            for (int u = 0; u < 4; ++u) {
                int k = kb + u;
                float kf = (float)(k - 128);
                float ixf = fmaf(kf, dxf, x0f);
                float iyf = fmaf(kf, dyf, y0f);
                float m = (k >= lo && k <= hi) ? 2.0f : 0.0f;    // valid * VOX
                int j0 = (int)ixf; j0 = min(max(j0, 0), 254);
                int i0 = (int)iyf; i0 = min(max(i0, 0), 254);
                float fx = ixf - (float)j0;
                float fy = iyf - (float)i0;
                float gxm = (1.f - fx) * m, fxm = fx * m;
                float gy = 1.f - fy;
                tap_acc(quad, i0, j0, gy * gxm, gy * fxm, fy * gxm, fy * fxm, acc);
            }
        }

        __shared__ float4 red[512];
        __shared__ float vb[2][N_DET];
        red[t] = acc;
        __syncthreads();
        if (t < 256) {
            float4 u = red[t], v = red[t + 256];
            float si0 = u.x + v.x, sa0 = u.y + v.y;
            float si1 = u.z + v.z, sa1 = u.w + v.w;
            vb[0][t] = si0 * expf(-sa0 * 2.0f);   // * exp(-att_sino * VOX)
            vb[1][t] = si1 * expf(-sa1 * 2.0f);
        }
        __syncthreads();
        if (t < 256) {
            float a0 = 0.f, a1 = 0.f;
            #pragma unroll
            for (int i = -2; i <= 2; ++i) {
                int dd = refl(t + i, N_DET);
                a0 += wblur.w[i + 2] * vb[0][dd];
                a1 += wblur.w[i + 2] * vb[1][dd];
            }
            out[t * N_ANG + a] = a0;                       // b=0
            out[(N_DET + t) * N_ANG + a] = a1;             // b=1
        }
    } else {
        // ---- V-mode: |sin| > |cos| (a in [91,269]); lane = sample k ----
        int idx = bx - NH_BLOCKS;
        int a = 91 + (idx >> 5);
        int dgrp = idx & 31;
        int lane = t & 63, w = t >> 6;
        int d = dgrp * 8 + w;
        AngTab tb = tab[a];
        float cf = tb.cf, snf = tb.snf;
        float df = (float)d - 127.5f;
        float hx = fmaf(df, cf, 127.5f);
        float hy = fmaf(df, snf, 127.5f);

        float4 acc = make_float4(0.f, 0.f, 0.f, 0.f);
        #pragma unroll
        for (int j = 0; j < 4; ++j) {
            int k = j * 64 + lane;
            float kf = (float)k - 127.5f;
            float ixf = fmaf(-kf, snf, hx);
            float iyf = fmaf(kf, cf, hy);
            float vmin = fminf(fminf(ixf, 255.0f - ixf), fminf(iyf, 255.0f - iyf));
            if (!__any(vmin > -EPS)) continue;
            float m = (vmin >= EPS) ? 2.0f : 0.0f;
            if (fabsf(vmin) < EPS) {                       // rare exact check
                double ss = (double)(2 * k - 255);
                double rr = (double)(2 * d - 255);
                double rc = __dmul_rn(rr, tb.c), rs = __dmul_rn(rr, tb.sn);
                double ixd = __dadd_rn(__dmul_rn(__dsub_rn(rc, __dmul_rn(ss, tb.sn)), 0.5), 127.5);
                double iyd = __dadd_rn(__dmul_rn(__dadd_rn(rs, __dmul_rn(ss, tb.c)), 0.5), 127.5);
                bool v = (ixd >= 0.0) && (ixd <= 255.0) && (iyd >= 0.0) && (iyd <= 255.0);
                m = v ? 2.0f : 0.0f;
            }
            int j0 = (int)ixf; j0 = min(max(j0, 0), 254);
            int i0 = (int)iyf; i0 = min(max(i0, 0), 254);
            float fx = ixf - (float)j0;
            float fy = iyf - (float)i0;
            float gxm = (1.f - fx) * m, fxm = fx * m;
            float gy = 1.f - fy;
            tap_acc(quad, i0, j0, gy * gxm, gy * fxm, fy * gxm, fy * fxm, acc);
        }

        #pragma unroll
        for (int off = 32; off; off >>= 1) {
            acc.x += __shfl_xor(acc.x, off);
            acc.y += __shfl_xor(acc.y, off);
            acc.z += __shfl_xor(acc.z, off);
            acc.w += __shfl_xor(acc.w, off);
        }
        if (lane == 0) part4[a * N_DET + d] = acc;
    }
}

// V-angles only: attenuation + detector-axis blur + transpose.
__global__ __launch_bounds__(256) void finish_v_k(const float4* __restrict__ part4,
                                                  float* __restrict__ out, W9 wt) {
    int d = threadIdx.x;
    int b = blockIdx.x / 179;
    int a = 91 + (blockIdx.x % 179);
    float4 s = part4[a * N_DET + d];
    float si = b ? s.z : s.x;
    float sa = b ? s.w : s.y;
    __shared__ float vb[N_DET];
    vb[d] = si * expf(-sa * 2.0f);
    __syncthreads();
    float acc = 0.f;
    #pragma unroll
    for (int i = -2; i <= 2; ++i) acc += wt.w[i + 2] * vb[refl(d + i, N_DET)];
    out[(b * N_DET + d) * N_ANG + a] = acc;
}

static void gauss_w(W9* wt, double sigma, int r, int pad_to_center4) {
    double tmp[9];
    double s = 0.0;
    for (int i = -r; i <= r; ++i) {
        double v = exp(-0.5 * ((double)i / sigma) * ((double)i / sigma));
        tmp[i + r] = v;
        s += v;
    }
    for (int i = 0; i < 9; ++i) wt->w[i] = 0.f;
    int off = pad_to_center4 ? (4 - r) : 0;
    for (int i = 0; i < 2 * r + 1; ++i) wt->w[i + off] = (float)(tmp[i] / s);
}

extern "C" void kernel_launch(void* const* d_in, const int* in_sizes, int n_in,
                              void* d_out, int out_size, void* d_ws, size_t ws_size,
                              hipStream_t stream) {
    const float* img = (const float*)d_in[0];
    const float* att = (const float*)d_in[1];
    float* out = (float*)d_out;

    char* ws = (char*)d_ws;
    AngTab* tab = (AngTab*)ws;                                  // 16 KiB slot
    float* pk = (float*)(ws + 16384);                           // 1 MiB (f32 float4)
    uint4* quad = (uint4*)(ws + 16384 + (1 << 20));             // 2 MiB (f16 quads)
    float4* part4 = (float4*)(ws + 16384 + 3 * (1 << 20));      // 1.47 MiB (V only)

    double sqrt_log2 = sqrt(log(2.0));
    double sigma_img = 4.0 / (4.0 * sqrt_log2) / 2.0;           // ~0.60056, r=2
    double sigma_att = 4.0 / (2.0 * sqrt_log2) / 2.0;           // ~1.20112, r=4
    W9 wimg_pad, wimg, watt;
    gauss_w(&wimg_pad, sigma_img, 2, 1);   // 5-tap centered in 9 (for blur4_k)
    gauss_w(&wimg, sigma_img, 2, 0);       // 5-tap at [0..4] (for finish)
    gauss_w(&watt, sigma_att, 4, 0);

    blur4_k<<<dim3(IMG, 4), IMG, 0, stream>>>(img, att, pk, wimg_pad, watt);
    quad_k<<<IMG, IMG, 0, stream>>>((const float4*)pk, quad, tab);
    proj_k<<<NH_BLOCKS + NV_BLOCKS, 512, 0, stream>>>(quad, tab, part4, out, wimg);
    finish_v_k<<<2 * 179, N_DET, 0, stream>>>(part4, out, wimg);
}